// Round 7
// baseline (1212.601 us; speedup 1.0000x reference)
//
#include <hip/hip_runtime.h>
#include <hip/hip_bf16.h>

// ---------------------------------------------------------------------------
// Equivariant conv block. MFMA 32x32x16 implicit GEMM, 2x2 reg tiles/wave.
//   C_in folded: 16 (s) + 48 (v) + 96 (t-sym) = 160; chunk-major layouts.
// R7 = R6 + (a) hoisted staging addresses (per-lane invariants in VGPRs,
// wave-uniform scalar delta per iter), (b) atomicAdd f32 epilogue into a
// single 4MB y (kills 200MB partial round-trip + combine kernel),
// (c) ksn=16 -> grid 1024 = 4 blocks/CU, (d) build_w split 4x.
// ---------------------------------------------------------------------------

using f4  = __attribute__((ext_vector_type(4)))  float;
using f16v= __attribute__((ext_vector_type(16))) float;
using s8  = __attribute__((ext_vector_type(8)))  short;  // 8 bf16

#define C_TOT 160
#define PZ_   37
#define PX_   38
#define NTAP  343
#define NROW  (4 * PZ_ * PZ_) // 5476 (b,z,y) rows per chunk
#define KSN   16

// conv LDS: A [row16][slot38][cg2][16B], row stride 1232B (data 1216 + 16 pad).
// A staged as 20 x 1024B chunks (slack clamped). B at 20480: [kx7][nt2][cg2][n32][16B].
#define AROW    1232
#define B_OFF   20480
#define LDS_SZ  (B_OFF + 14336)    // 34816

__device__ __forceinline__ void gl_lds16(const void* g, void* l) {
    __builtin_amdgcn_global_load_lds(
        (const __attribute__((address_space(1))) unsigned int*)g,
        (__attribute__((address_space(3))) unsigned int*)l, 16, 0, 0);
}

__device__ __forceinline__ void pair_ij(int p, int& i, int& j) {
    if (p < 3)      { i = p; j = p; }
    else if (p == 3){ i = 0; j = 1; }
    else if (p == 4){ i = 0; j = 2; }
    else            { i = 1; j = 2; }
}

struct bf2 { __hip_bfloat16 x, y; };

// ---------------------------------------------------------------------------
// Build x_t, chunk-major: xt[chunk][brow][s][16ch], brow=(b*37+z)*37+y.
// ---------------------------------------------------------------------------
__global__ void build_xt_kernel(const float* __restrict__ sv,
                                __hip_bfloat16* __restrict__ xt)
{
    __shared__ float row[32 * 66];
    const int bid = blockIdx.x;                 // (b*37 + z)*37 + y
    const int y = bid % 37, z = (bid / 37) % 37, b = bid / 1369;
    const bool interior = (z >= 3 && z < 35 && y >= 3 && y < 35);
    if (interior) {
        const float* src = sv + (size_t)b * 2097152 + (z - 3) * 1024 + (y - 3) * 32;
        for (int f = threadIdx.x; f < 2048; f += 256) {
            int ch = f >> 5, x = f & 31;
            row[x * 66 + ch] = src[(size_t)ch * 32768 + x];
        }
    }
    __syncthreads();
    for (int e2 = threadIdx.x; e2 < PX_ * 80; e2 += 256) {
        const int s = e2 / 80, cp = e2 % 80, c = cp * 2;
        float v0 = 0.f, v1 = 0.f;
        if (interior && s >= 3 && s < 35) {
            const int x = s - 3;
            if (c < 64) {
                v0 = row[x * 66 + c];
                v1 = row[x * 66 + c + 1];
            } else {
                int q = c - 64, u = q / 6, p = q % 6, i, j;
                pair_ij(p, i, j);
                v0 = row[x * 66 + 16 + u * 3 + i] * row[x * 66 + 16 + u * 3 + j];
                pair_ij(p + 1, i, j);
                v1 = row[x * 66 + 16 + u * 3 + i] * row[x * 66 + 16 + u * 3 + j];
            }
        }
        bf2 w{__float2bfloat16(v0), __float2bfloat16(v1)};
        const int chunk = c >> 4, cw = c & 15;
        *(bf2*)(xt + ((size_t)chunk * NROW + bid) * 608 + s * 16 + cw) = w;
    }
}

// ---------------------------------------------------------------------------
// Build W, chunk-major: wl[chunk][tap][n][16ch]. Grid NTAP*4 (j-range split).
// ---------------------------------------------------------------------------
__global__ void build_w_kernel(
    const float* __restrict__ b_ss, const float* __restrict__ w_ss,
    const float* __restrict__ b_sv, const float* __restrict__ w_sv,
    const float* __restrict__ b_st, const float* __restrict__ w_st,
    const float* __restrict__ b_vs, const float* __restrict__ w_vs,
    const float* __restrict__ b_vv, const float* __restrict__ w_vv,
    const float* __restrict__ b_vt, const float* __restrict__ w_vt,
    __hip_bfloat16* __restrict__ wl)
{
    __shared__ float L[750];
    __shared__ float W[12288];
    const int tap = blockIdx.x >> 2;
    const int jq  = (blockIdx.x & 3) * 10;
    const int tid = threadIdx.x;
    for (int r = tid; r < 750; r += 256) {
        float v;
        if (r < 3)        v = b_ss[r * NTAP + tap];
        else if (r < 12)  v = b_sv[(r - 3) * NTAP + tap];
        else if (r < 93)  v = b_st[(r - 12) * NTAP + tap];
        else if (r < 102) v = b_vs[(r - 93) * NTAP + tap];
        else if (r < 183) v = b_vv[(r - 102) * NTAP + tap];
        else              v = b_vt[(r - 183) * NTAP + tap];
        L[r] = v;
    }
    for (int r = tid; r < 12288; r += 256) {
        float v;
        if (r < 768)       v = w_ss[r];
        else if (r < 1536) v = w_sv[r - 768];
        else if (r < 3840) v = w_st[r - 1536];
        else if (r < 4608) v = w_vs[r - 3840];
        else if (r < 6912) v = w_vv[r - 4608];
        else               v = w_vt[r - 6912];
        W[r] = v;
    }
    __syncthreads();
    for (int j = jq; j < jq + 10; ++j) {
        const int idx = j * 256 + tid;
        const int c = idx % C_TOT, n = idx / C_TOT;
        float acc = 0.f;
        if (n < 16) {
            const int u = n;
            if (c < 16) {
                for (int t = 0; t < 3; ++t) acc += W[(u*16 + c)*3 + t] * L[t];
            } else if (c < 64) {
                int mm = (c-16)/3, di = (c-16)%3;
                for (int t = 0; t < 3; ++t) acc += W[768 + (u*16+mm)*3 + t] * L[3 + t*3 + di];
            } else {
                int q = c-64, mm = q/6, p = q%6, i, jj;
                pair_ij(p, i, jj);
                int d1 = i*3+jj, d2 = jj*3+i;
                for (int t = 0; t < 9; ++t) {
                    float bs = L[12 + t*9 + d1];
                    if (i != jj) bs += L[12 + t*9 + d2];
                    acc += W[1536 + (u*16+mm)*9 + t] * bs;
                }
            }
        } else {
            const int u = (n-16)/3, dn = (n-16)%3;
            if (c < 16) {
                for (int t = 0; t < 3; ++t) acc += W[3840 + (u*16+c)*3 + t] * L[93 + t*3 + dn];
            } else if (c < 64) {
                int mm = (c-16)/3, di = (c-16)%3;
                for (int t = 0; t < 9; ++t)
                    acc += W[4608 + (u*16+mm)*9 + t] * L[102 + (t*3+dn)*3 + di];
            } else {
                int q = c-64, mm = q/6, p = q%6, i, jj;
                pair_ij(p, i, jj);
                int d1 = i*3+jj, d2 = jj*3+i;
                for (int t = 0; t < 21; ++t) {
                    float bs = L[183 + (t*3+dn)*9 + d1];
                    if (i != jj) bs += L[183 + (t*3+dn)*9 + d2];
                    acc += W[6912 + (u*16+mm)*21 + t] * bs;
                }
            }
        }
        const int chunk = c >> 4, cw = c & 15;
        wl[((size_t)chunk * NTAP + tap) * 1024 + (size_t)n * 16 + cw] =
            __float2bfloat16(acc);
    }
}

// ---------------------------------------------------------------------------
// Conv. Grid 64*KSN = 1024, 4 blocks/CU. Staging addresses: per-lane
// invariant offsets precomputed once (VGPR), per-iter only a wave-uniform
// scalar delta -> saddr+voffset DMA, ~0 VALU per issue.
// Epilogue: atomicAdd f32 into y[b][n][4096] (zeroed by memset).
// ---------------------------------------------------------------------------
__global__ __launch_bounds__(256, 4) void conv_mfma_kernel(
    const __hip_bfloat16* __restrict__ xt,
    const __hip_bfloat16* __restrict__ wl,
    float* __restrict__ y)
{
    __shared__ __align__(16) char lds[LDS_SZ];

    const int bid  = blockIdx.x;
    const int low3 = bid & 7;
    const int rest = bid >> 3;
    const int ks   = rest % KSN;
    const int mb   = (rest / KSN) * 8 + low3;
    const int b    = mb >> 4;
    const int oz0 = ((mb >> 2) & 3) * 4;
    const int oy0 = (mb & 3) * 4;

    const int tid  = threadIdx.x;
    const int w    = tid >> 6;          // x-quarter
    const int lane = tid & 63;
    const int m    = lane & 31;
    const int h    = lane >> 5;         // k-half (8-ch group)

    // ---- per-lane invariant staging offsets (elements) + LDS dsts ----
    int  invA[5];  char* dstA[5];
#pragma unroll
    for (int k = 0; k < 5; ++k) {
        const int i = w + 4 * k;                 // < 20 always
        const int o = i * 1024 + lane * 16;
        int r = o / AROW;
        int rem = o - r * AROW;
        if (r > 15) { r = 15; rem = 0; }         // slack: dummy src
        if (rem >= 1216) rem = 0;                // row pad: dummy src
        const int s  = rem >> 5;
        const int cg = ((rem >> 4) & 1) ^ ((s >> 1) & 1);
        const int base_row = (b * PZ_ + 2 * (oz0 + (r >> 2))) * PZ_
                           + 2 * (oy0 + (r & 3));
        invA[k] = base_row * 608 + s * 16 + cg * 8;
        dstA[k] = lds + i * 1024;
    }
    int  invB[4];  char* dstB[4];  int nB = 0;
#pragma unroll
    for (int k = 0; k < 4; ++k) {
        const int i = w + 4 * k;
        if (i < 14) {
            const int kx = i >> 1, nt = i & 1;
            invB[k] = kx * 1024 + (nt * 32 + m) * 16 + h * 8;
            dstB[k] = lds + B_OFF + i * 1024;
            nB = k + 1;
        }
    }

    f16v acc[2][2];
    for (int t = 0; t < 2; ++t)
        for (int n = 0; n < 2; ++n)
            for (int k = 0; k < 16; ++k) acc[t][n][k] = 0.f;

    const int rA0   = ((m >> 4) << 2) + ((m >> 2) & 3);   // LDS row for t=0
    const int sbase = (w << 3) + ((m & 3) << 1);          // + kx -> x slot

    for (int chunk = 0; chunk < 10; ++chunk) {
        for (int zy = ks; zy < 49; zy += KSN) {
            const int kz = zy / 7, ky = zy - kz * 7;
            const int u_a = (chunk * NROW + kz * PZ_ + ky) * 608;   // uniform
            const int u_b = (chunk * NTAP + zy * 7) * 1024;         // uniform
            __syncthreads();

#pragma unroll
            for (int k = 0; k < 5; ++k)
                gl_lds16(xt + u_a + invA[k], dstA[k]);
#pragma unroll
            for (int k = 0; k < 4; ++k)
                if (k < nB) gl_lds16(wl + u_b + invB[k], dstB[k]);
            __syncthreads();                           // drains lds-DMA

#pragma unroll
            for (int kx = 0; kx < 7; ++kx) {
                const int s   = sbase + kx;
                const int cgp = h ^ ((s >> 1) & 1);
                const char* ap = lds + rA0 * AROW + s * 32 + cgp * 16;
                const s8 a0 = *(const s8*)(ap);
                const s8 a1 = *(const s8*)(ap + 8 * AROW);
                const char* bp = lds + B_OFF + kx * 2048 + h * 512 + m * 16;
                const s8 b0 = *(const s8*)(bp);
                const s8 b1 = *(const s8*)(bp + 1024);
                acc[0][0] = __builtin_amdgcn_mfma_f32_32x32x16_bf16(a0, b0, acc[0][0], 0, 0, 0);
                acc[0][1] = __builtin_amdgcn_mfma_f32_32x32x16_bf16(a0, b1, acc[0][1], 0, 0, 0);
                acc[1][0] = __builtin_amdgcn_mfma_f32_32x32x16_bf16(a1, b0, acc[1][0], 0, 0, 0);
                acc[1][1] = __builtin_amdgcn_mfma_f32_32x32x16_bf16(a1, b1, acc[1][1], 0, 0, 0);
            }
        }
    }

    // ---- epilogue: atomic accumulate into y ----
    // C/D 32x32: col(n)=lane&31, row m32=(reg&3)+8*(reg>>2)+4*h  [m74/m101]
    const int nl = lane & 31;
#pragma unroll
    for (int nt = 0; nt < 2; ++nt) {
        float* bn = y + ((size_t)(b * 64 + nt * 32 + nl)) * 4096;
#pragma unroll
        for (int t = 0; t < 2; ++t) {
#pragma unroll
            for (int q = 0; q < 4; ++q) {
                const int rr  = 2 * q + h;
                const int my  = rr & 3;
                const int mz  = t * 2 + (rr >> 2);
                float* p = bn + (oz0 + mz) * 256 + (oy0 + my) * 16 + 4 * w;
                atomicAdd(p + 0, acc[t][nt][4*q]);
                atomicAdd(p + 1, acc[t][nt][4*q+1]);
                atomicAdd(p + 2, acc[t][nt][4*q+2]);
                atomicAdd(p + 3, acc[t][nt][4*q+3]);
            }
        }
    }
}

// ---------------------------------------------------------------------------
// Per-channel sum of squares over y. 64 blocks (one per n).
// ---------------------------------------------------------------------------
__global__ void sums_kernel(const float* __restrict__ y,
                            float* __restrict__ sums)
{
    const int n = blockIdx.x;
    float s = 0.f;
    for (int i = threadIdx.x; i < 16384; i += 256) {
        const int b = i >> 12, sp = i & 4095;
        float v = y[((size_t)b * 64 + n) * 4096 + sp];
        s += v * v;
    }
    __shared__ float red[256];
    red[threadIdx.x] = s;
    __syncthreads();
    for (int st = 128; st > 0; st >>= 1) {
        if (threadIdx.x < st) red[threadIdx.x] += red[threadIdx.x + st];
        __syncthreads();
    }
    if (threadIdx.x == 0) sums[n] = red[0];
}

// ---------------------------------------------------------------------------
__global__ void finalize_kernel(const float* __restrict__ y,
                                const float* __restrict__ sums,
                                const float* __restrict__ g_s,
                                const float* __restrict__ g_v,
                                const float* __restrict__ bias_s,
                                float* __restrict__ out)
{
    const int idx = blockIdx.x * 256 + threadIdx.x;   // exact grid, 1M
    const int n = (idx >> 12) & 63;
    float v = y[idx];
    if (n < 16) {
        float var = sums[n] * (1.0f / 16384.0f);
        float sc  = g_s[n] / sqrtf(var + 1e-5f);
        v = fmaxf(v * sc + bias_s[n], 0.f);
    } else {
        int u = (n - 16) / 3;
        float sum = sums[16 + u*3] + sums[17 + u*3] + sums[18 + u*3];
        float var = sum * (1.0f / 49152.0f);
        v = v * (g_v[u] / sqrtf(var + 1e-5f));
    }
    out[idx] = v;
}

// ---------------------------------------------------------------------------
extern "C" void kernel_launch(void* const* d_in, const int* in_sizes, int n_in,
                              void* d_out, int out_size, void* d_ws, size_t ws_size,
                              hipStream_t stream)
{
    const float* sv    = (const float*)d_in[0];
    const float* b_ss  = (const float*)d_in[1];
    const float* w_ss  = (const float*)d_in[2];
    const float* b_sv  = (const float*)d_in[3];
    const float* w_sv  = (const float*)d_in[4];
    const float* b_st  = (const float*)d_in[5];
    const float* w_st  = (const float*)d_in[6];
    const float* b_vs  = (const float*)d_in[7];
    const float* w_vs  = (const float*)d_in[8];
    const float* b_vv  = (const float*)d_in[9];
    const float* w_vv  = (const float*)d_in[10];
    const float* b_vt  = (const float*)d_in[11];
    const float* w_vt  = (const float*)d_in[12];
    const float* bn_gs = (const float*)d_in[13];
    const float* bn_gv = (const float*)d_in[14];
    const float* bias_s= (const float*)d_in[15];
    float* out = (float*)d_out;

    char* ws = (char*)d_ws;
    constexpr size_t XT_BYTES = (size_t)10 * NROW * 1216;   // 66,588,160
    constexpr size_t WL_BYTES = (size_t)10 * NTAP * 2048;   //  7,024,640
    constexpr size_t Y_BYTES  = (size_t)4 * 64 * 4096 * 4;  //  4,194,304

    __hip_bfloat16* xt = (__hip_bfloat16*)ws;
    __hip_bfloat16* wl = (__hip_bfloat16*)(ws + XT_BYTES);
    float* y    = (float*)(ws + XT_BYTES + WL_BYTES);
    float* sums = (float*)(ws + XT_BYTES + WL_BYTES + Y_BYTES);

    hipMemsetAsync(y, 0, Y_BYTES, stream);   // atomic accumulate target

    build_xt_kernel<<<4 * 37 * 37, 256, 0, stream>>>(sv, xt);
    build_w_kernel<<<NTAP * 4, 256, 0, stream>>>(
        b_ss, w_ss, b_sv, w_sv, b_st, w_st, b_vs, w_vs, b_vv, w_vv, b_vt, w_vt, wl);
    conv_mfma_kernel<<<64 * KSN, 256, 0, stream>>>(xt, wl, y);
    sums_kernel<<<64, 256, 0, stream>>>(y, sums);
    finalize_kernel<<<4096, 256, 0, stream>>>(y, sums, bn_gs, bn_gv, bias_s, out);
}

// Round 8
// 330.916 us; speedup vs baseline: 3.6644x; 3.6644x over previous
//
#include <hip/hip_runtime.h>
#include <hip/hip_bf16.h>

// ---------------------------------------------------------------------------
// Equivariant conv block. MFMA 32x32x16 implicit GEMM, 2x2 reg tiles/wave.
//   C_in folded: 16 (s) + 48 (v) + 96 (t-sym) = 160; chunk-major layouts.
// R8 = R6 structure (K-split partials + combine, NO atomics — R7's contended
// atomicAdd epilogue cost 890us) + R7's hoisted staging addresses (proved
// 5x VALU cut) + ksn=16 (4 blocks/CU; staged bytes are ksn-invariant) +
// combine fused with sum-of-squares.
// ---------------------------------------------------------------------------

using f4  = __attribute__((ext_vector_type(4)))  float;
using f16v= __attribute__((ext_vector_type(16))) float;
using s8  = __attribute__((ext_vector_type(8)))  short;  // 8 bf16

#define C_TOT 160
#define PZ_   37
#define NTAP  343
#define NROW  (4 * PZ_ * PZ_) // 5476 (b,z,y) rows per chunk

// conv LDS: A [row16][slot38][cg2][16B], row stride 1232B (data 1216 + 16 pad).
// A staged as 20 x 1024B chunks (slack clamped). B at 20480: [kx7][nt2][cg2][n32][16B].
#define AROW    1232
#define B_OFF   20480
#define LDS_SZ  (B_OFF + 14336)    // 34816 (x4 blocks = 139264 <= 160KB)

__device__ __forceinline__ void gl_lds16(const void* g, void* l) {
    __builtin_amdgcn_global_load_lds(
        (const __attribute__((address_space(1))) unsigned int*)g,
        (__attribute__((address_space(3))) unsigned int*)l, 16, 0, 0);
}

__device__ __forceinline__ void pair_ij(int p, int& i, int& j) {
    if (p < 3)      { i = p; j = p; }
    else if (p == 3){ i = 0; j = 1; }
    else if (p == 4){ i = 0; j = 2; }
    else            { i = 1; j = 2; }
}

struct bf2 { __hip_bfloat16 x, y; };

// ---------------------------------------------------------------------------
// Build x_t, chunk-major: xt[chunk][brow][s][16ch], brow=(b*37+z)*37+y.
// ---------------------------------------------------------------------------
__global__ void build_xt_kernel(const float* __restrict__ sv,
                                __hip_bfloat16* __restrict__ xt)
{
    __shared__ float row[32 * 66];
    const int bid = blockIdx.x;                 // (b*37 + z)*37 + y
    const int y = bid % 37, z = (bid / 37) % 37, b = bid / 1369;
    const bool interior = (z >= 3 && z < 35 && y >= 3 && y < 35);
    if (interior) {
        const float* src = sv + (size_t)b * 2097152 + (z - 3) * 1024 + (y - 3) * 32;
        for (int f = threadIdx.x; f < 2048; f += 256) {
            int ch = f >> 5, x = f & 31;
            row[x * 66 + ch] = src[(size_t)ch * 32768 + x];
        }
    }
    __syncthreads();
    for (int e2 = threadIdx.x; e2 < 38 * 80; e2 += 256) {
        const int s = e2 / 80, cp = e2 % 80, c = cp * 2;
        float v0 = 0.f, v1 = 0.f;
        if (interior && s >= 3 && s < 35) {
            const int x = s - 3;
            if (c < 64) {
                v0 = row[x * 66 + c];
                v1 = row[x * 66 + c + 1];
            } else {
                int q = c - 64, u = q / 6, p = q % 6, i, j;
                pair_ij(p, i, j);
                v0 = row[x * 66 + 16 + u * 3 + i] * row[x * 66 + 16 + u * 3 + j];
                pair_ij(p + 1, i, j);
                v1 = row[x * 66 + 16 + u * 3 + i] * row[x * 66 + 16 + u * 3 + j];
            }
        }
        bf2 w{__float2bfloat16(v0), __float2bfloat16(v1)};
        const int chunk = c >> 4, cw = c & 15;
        *(bf2*)(xt + ((size_t)chunk * NROW + bid) * 608 + s * 16 + cw) = w;
    }
}

// ---------------------------------------------------------------------------
// Build W, chunk-major: wl[chunk][tap][n][16ch]. Grid NTAP*4 (j-range split).
// ---------------------------------------------------------------------------
__global__ void build_w_kernel(
    const float* __restrict__ b_ss, const float* __restrict__ w_ss,
    const float* __restrict__ b_sv, const float* __restrict__ w_sv,
    const float* __restrict__ b_st, const float* __restrict__ w_st,
    const float* __restrict__ b_vs, const float* __restrict__ w_vs,
    const float* __restrict__ b_vv, const float* __restrict__ w_vv,
    const float* __restrict__ b_vt, const float* __restrict__ w_vt,
    __hip_bfloat16* __restrict__ wl)
{
    __shared__ float L[750];
    __shared__ float W[12288];
    const int tap = blockIdx.x >> 2;
    const int jq  = (blockIdx.x & 3) * 10;
    const int tid = threadIdx.x;
    for (int r = tid; r < 750; r += 256) {
        float v;
        if (r < 3)        v = b_ss[r * NTAP + tap];
        else if (r < 12)  v = b_sv[(r - 3) * NTAP + tap];
        else if (r < 93)  v = b_st[(r - 12) * NTAP + tap];
        else if (r < 102) v = b_vs[(r - 93) * NTAP + tap];
        else if (r < 183) v = b_vv[(r - 102) * NTAP + tap];
        else              v = b_vt[(r - 183) * NTAP + tap];
        L[r] = v;
    }
    for (int r = tid; r < 12288; r += 256) {
        float v;
        if (r < 768)       v = w_ss[r];
        else if (r < 1536) v = w_sv[r - 768];
        else if (r < 3840) v = w_st[r - 1536];
        else if (r < 4608) v = w_vs[r - 3840];
        else if (r < 6912) v = w_vv[r - 4608];
        else               v = w_vt[r - 6912];
        W[r] = v;
    }
    __syncthreads();
    for (int j = jq; j < jq + 10; ++j) {
        const int idx = j * 256 + tid;
        const int c = idx % C_TOT, n = idx / C_TOT;
        float acc = 0.f;
        if (n < 16) {
            const int u = n;
            if (c < 16) {
                for (int t = 0; t < 3; ++t) acc += W[(u*16 + c)*3 + t] * L[t];
            } else if (c < 64) {
                int mm = (c-16)/3, di = (c-16)%3;
                for (int t = 0; t < 3; ++t) acc += W[768 + (u*16+mm)*3 + t] * L[3 + t*3 + di];
            } else {
                int q = c-64, mm = q/6, p = q%6, i, jj;
                pair_ij(p, i, jj);
                int d1 = i*3+jj, d2 = jj*3+i;
                for (int t = 0; t < 9; ++t) {
                    float bs = L[12 + t*9 + d1];
                    if (i != jj) bs += L[12 + t*9 + d2];
                    acc += W[1536 + (u*16+mm)*9 + t] * bs;
                }
            }
        } else {
            const int u = (n-16)/3, dn = (n-16)%3;
            if (c < 16) {
                for (int t = 0; t < 3; ++t) acc += W[3840 + (u*16+c)*3 + t] * L[93 + t*3 + dn];
            } else if (c < 64) {
                int mm = (c-16)/3, di = (c-16)%3;
                for (int t = 0; t < 9; ++t)
                    acc += W[4608 + (u*16+mm)*9 + t] * L[102 + (t*3+dn)*3 + di];
            } else {
                int q = c-64, mm = q/6, p = q%6, i, jj;
                pair_ij(p, i, jj);
                int d1 = i*3+jj, d2 = jj*3+i;
                for (int t = 0; t < 21; ++t) {
                    float bs = L[183 + (t*3+dn)*9 + d1];
                    if (i != jj) bs += L[183 + (t*3+dn)*9 + d2];
                    acc += W[6912 + (u*16+mm)*21 + t] * bs;
                }
            }
        }
        const int chunk = c >> 4, cw = c & 15;
        wl[((size_t)chunk * NTAP + tap) * 1024 + (size_t)n * 16 + cw] =
            __float2bfloat16(acc);
    }
}

// ---------------------------------------------------------------------------
// Conv. Grid 64*ksn. bid = (mb>>3)*(8*ksn) + ks*8 + (mb&7). Hoisted staging:
// per-lane invariant offsets in VGPRs, wave-uniform delta per iter.
// Epilogue: direct f4 stores of partials y4[ks][b][n][4096].
// ---------------------------------------------------------------------------
__global__ __launch_bounds__(256, 4) void conv_mfma_kernel(
    const __hip_bfloat16* __restrict__ xt,
    const __hip_bfloat16* __restrict__ wl,
    float* __restrict__ y4, int ksn)
{
    __shared__ __align__(16) char lds[LDS_SZ];

    const int bid  = blockIdx.x;
    const int low3 = bid & 7;
    const int rest = bid >> 3;
    const int ks   = rest % ksn;
    const int mb   = (rest / ksn) * 8 + low3;
    const int b    = mb >> 4;
    const int oz0 = ((mb >> 2) & 3) * 4;
    const int oy0 = (mb & 3) * 4;

    const int tid  = threadIdx.x;
    const int w    = tid >> 6;          // x-quarter
    const int lane = tid & 63;
    const int m    = lane & 31;
    const int h    = lane >> 5;         // k-half (8-ch group)

    // ---- per-lane invariant staging offsets (elements) + LDS dsts ----
    int  invA[5];  char* dstA[5];
#pragma unroll
    for (int k = 0; k < 5; ++k) {
        const int i = w + 4 * k;                 // < 20 always
        const int o = i * 1024 + lane * 16;
        int r = o / AROW;
        int rem = o - r * AROW;
        if (r > 15) { r = 15; rem = 0; }         // slack: dummy src
        if (rem >= 1216) rem = 0;                // row pad: dummy src
        const int s  = rem >> 5;
        const int cg = ((rem >> 4) & 1) ^ ((s >> 1) & 1);
        const int base_row = (b * PZ_ + 2 * (oz0 + (r >> 2))) * PZ_
                           + 2 * (oy0 + (r & 3));
        invA[k] = base_row * 608 + s * 16 + cg * 8;
        dstA[k] = lds + i * 1024;
    }
    int  invB[4];  char* dstB[4];  int nB = 0;
#pragma unroll
    for (int k = 0; k < 4; ++k) {
        const int i = w + 4 * k;
        if (i < 14) {
            const int kx = i >> 1, nt = i & 1;
            invB[k] = kx * 1024 + (nt * 32 + m) * 16 + h * 8;
            dstB[k] = lds + B_OFF + i * 1024;
            nB = k + 1;
        }
    }

    f16v acc[2][2];
    for (int t = 0; t < 2; ++t)
        for (int n = 0; n < 2; ++n)
            for (int k = 0; k < 16; ++k) acc[t][n][k] = 0.f;

    const int rA0   = ((m >> 4) << 2) + ((m >> 2) & 3);   // LDS row for t=0
    const int sbase = (w << 3) + ((m & 3) << 1);          // + kx -> x slot

    for (int chunk = 0; chunk < 10; ++chunk) {
        for (int zy = ks; zy < 49; zy += ksn) {
            const int kz = zy / 7, ky = zy - kz * 7;
            const int u_a = (chunk * NROW + kz * PZ_ + ky) * 608;   // uniform
            const int u_b = (chunk * NTAP + zy * 7) * 1024;         // uniform
            __syncthreads();

#pragma unroll
            for (int k = 0; k < 5; ++k)
                gl_lds16(xt + u_a + invA[k], dstA[k]);
#pragma unroll
            for (int k = 0; k < 4; ++k)
                if (k < nB) gl_lds16(wl + u_b + invB[k], dstB[k]);
            __syncthreads();                           // drains lds-DMA

#pragma unroll
            for (int kx = 0; kx < 7; ++kx) {
                const int s   = sbase + kx;
                const int cgp = h ^ ((s >> 1) & 1);
                const char* ap = lds + rA0 * AROW + s * 32 + cgp * 16;
                const s8 a0 = *(const s8*)(ap);
                const s8 a1 = *(const s8*)(ap + 8 * AROW);
                const char* bp = lds + B_OFF + kx * 2048 + h * 512 + m * 16;
                const s8 b0 = *(const s8*)(bp);
                const s8 b1 = *(const s8*)(bp + 1024);
                acc[0][0] = __builtin_amdgcn_mfma_f32_32x32x16_bf16(a0, b0, acc[0][0], 0, 0, 0);
                acc[0][1] = __builtin_amdgcn_mfma_f32_32x32x16_bf16(a0, b1, acc[0][1], 0, 0, 0);
                acc[1][0] = __builtin_amdgcn_mfma_f32_32x32x16_bf16(a1, b0, acc[1][0], 0, 0, 0);
                acc[1][1] = __builtin_amdgcn_mfma_f32_32x32x16_bf16(a1, b1, acc[1][1], 0, 0, 0);
            }
        }
    }

    // ---- epilogue: direct f4 partial stores ----
    // C/D 32x32: col(n)=lane&31, row m32=(reg&3)+8*(reg>>2)+4*h  [m74/m101]
    const int nl = lane & 31;
#pragma unroll
    for (int nt = 0; nt < 2; ++nt) {
        float* bn = y4 + (size_t)ks * 1048576 +
                    ((size_t)(b * 64 + nt * 32 + nl)) * 4096;
#pragma unroll
        for (int t = 0; t < 2; ++t) {
#pragma unroll
            for (int q = 0; q < 4; ++q) {
                const int rr  = 2 * q + h;
                const int my  = rr & 3;
                const int mz  = t * 2 + (rr >> 2);
                f4 v = { acc[t][nt][4*q], acc[t][nt][4*q+1],
                         acc[t][nt][4*q+2], acc[t][nt][4*q+3] };
                *(f4*)(bn + (oz0 + mz) * 256 + (oy0 + my) * 16 + 4 * w) = v;
            }
        }
    }
}

// ---------------------------------------------------------------------------
// Combine ksn partials into slice 0 + per-(n,b) sum of squares. 256 blocks.
// ---------------------------------------------------------------------------
__global__ void combine_reduce_kernel(float* __restrict__ y4,
                                      float* __restrict__ sums2, int ksn)
{
    const int n = blockIdx.x & 63, q = blockIdx.x >> 6;
    const size_t base = ((size_t)q * 64 + n) * 4096;
    float s = 0.f;
    for (int i = threadIdx.x; i < 1024; i += 256) {
        size_t off = base + (size_t)i * 4;
        f4 v = *(const f4*)(y4 + off);
        for (int k = 1; k < ksn; ++k) v += *(const f4*)(y4 + off + (size_t)k * 1048576);
        *(f4*)(y4 + off) = v;
        s += v.x * v.x + v.y * v.y + v.z * v.z + v.w * v.w;
    }
    __shared__ float red[256];
    red[threadIdx.x] = s;
    __syncthreads();
    for (int st = 128; st > 0; st >>= 1) {
        if (threadIdx.x < st) red[threadIdx.x] += red[threadIdx.x + st];
        __syncthreads();
    }
    if (threadIdx.x == 0) sums2[n * 4 + q] = red[0];
}

// ---------------------------------------------------------------------------
__global__ void finalize_kernel(const float* __restrict__ y,
                                const float* __restrict__ sums2,
                                const float* __restrict__ g_s,
                                const float* __restrict__ g_v,
                                const float* __restrict__ bias_s,
                                float* __restrict__ out)
{
    const int idx = blockIdx.x * 256 + threadIdx.x;   // exact grid, 1M
    const int n = (idx >> 12) & 63;
    float v = y[idx];
    if (n < 16) {
        float sum = sums2[n*4] + sums2[n*4+1] + sums2[n*4+2] + sums2[n*4+3];
        float var = sum * (1.0f / 16384.0f);
        float sc  = g_s[n] / sqrtf(var + 1e-5f);
        v = fmaxf(v * sc + bias_s[n], 0.f);
    } else {
        int u = (n - 16) / 3;
        float sum = 0.f;
        for (int k = 0; k < 12; ++k) sum += sums2[(16 + u * 3) * 4 + k];
        float var = sum * (1.0f / 49152.0f);
        v = v * (g_v[u] / sqrtf(var + 1e-5f));
    }
    out[idx] = v;
}

// ---------------------------------------------------------------------------
extern "C" void kernel_launch(void* const* d_in, const int* in_sizes, int n_in,
                              void* d_out, int out_size, void* d_ws, size_t ws_size,
                              hipStream_t stream)
{
    const float* sv    = (const float*)d_in[0];
    const float* b_ss  = (const float*)d_in[1];
    const float* w_ss  = (const float*)d_in[2];
    const float* b_sv  = (const float*)d_in[3];
    const float* w_sv  = (const float*)d_in[4];
    const float* b_st  = (const float*)d_in[5];
    const float* w_st  = (const float*)d_in[6];
    const float* b_vs  = (const float*)d_in[7];
    const float* w_vs  = (const float*)d_in[8];
    const float* b_vv  = (const float*)d_in[9];
    const float* w_vv  = (const float*)d_in[10];
    const float* b_vt  = (const float*)d_in[11];
    const float* w_vt  = (const float*)d_in[12];
    const float* bn_gs = (const float*)d_in[13];
    const float* bn_gv = (const float*)d_in[14];
    const float* bias_s= (const float*)d_in[15];
    float* out = (float*)d_out;

    char* ws = (char*)d_ws;
    constexpr size_t XT_BYTES = (size_t)10 * NROW * 1216;   // 66,588,160
    constexpr size_t WL_BYTES = (size_t)10 * NTAP * 2048;   //  7,024,640
    constexpr size_t SLICE    = (size_t)4 * 64 * 4096 * 4;  //  4,194,304

    int ksn = 16;
    if (ws_size < XT_BYTES + WL_BYTES + 16 * SLICE + 4096) ksn = 12;
    if (ws_size < XT_BYTES + WL_BYTES + 12 * SLICE + 4096) ksn = 8;

    __hip_bfloat16* xt = (__hip_bfloat16*)ws;
    __hip_bfloat16* wl = (__hip_bfloat16*)(ws + XT_BYTES);
    float* y4    = (float*)(ws + XT_BYTES + WL_BYTES);
    float* sums2 = (float*)(ws + XT_BYTES + WL_BYTES + (size_t)ksn * SLICE);

    build_xt_kernel<<<4 * 37 * 37, 256, 0, stream>>>(sv, xt);
    build_w_kernel<<<NTAP * 4, 256, 0, stream>>>(
        b_ss, w_ss, b_sv, w_sv, b_st, w_st, b_vs, w_vs, b_vv, w_vv, b_vt, w_vt, wl);
    conv_mfma_kernel<<<64 * ksn, 256, 0, stream>>>(xt, wl, y4, ksn);
    combine_reduce_kernel<<<256, 256, 0, stream>>>(y4, sums2, ksn);
    finalize_kernel<<<4096, 256, 0, stream>>>(y4, sums2, bn_gs, bn_gv, bias_s, out);
}

// Round 9
// 279.466 us; speedup vs baseline: 4.3390x; 1.1841x over previous
//
#include <hip/hip_runtime.h>
#include <hip/hip_bf16.h>

// ---------------------------------------------------------------------------
// Equivariant conv block. MFMA 32x32x16 implicit GEMM, 2x2 reg tiles/wave.
//   C_in folded: 16 (s) + 48 (v) + 96 (t-sym) = 160; chunk-major layouts.
// R9 = R8 + (a) BALANCED flat K-split (t=ks..490 step 16; old per-ks zy loop
// gave ks=0 40 iters vs 30 -> 33% tail), (b) coalesced two-pass LDS-transpose
// epilogue with bf16 partials (old direct stores: lane-stride 16KB, WRITE
// 102MB for 64MB data), (c) combine reads bf16 partials, (d) build_xt+build_w
// merged into one launch.
// ---------------------------------------------------------------------------

using f4  = __attribute__((ext_vector_type(4)))  float;
using f16v= __attribute__((ext_vector_type(16))) float;
using s8  = __attribute__((ext_vector_type(8)))  short;  // 8 bf16

#define C_TOT 160
#define PZ_   37
#define NTAP  343
#define NROW  (4 * PZ_ * PZ_)   // 5476 (b,z,y) rows per chunk
#define KSN   16
#define NT5   490               // 10 chunks * 49 zy
#define SLICE_E 1048576         // bf16 elems per partial slice (4*64*4096)

// conv LDS: A [row16][slot38][cg2][16B], row stride 1232B (data 1216 + 16 pad).
// A staged as 20 x 1024B chunks (slack clamped). B at 20480: [kx7][nt2][cg2][n32][16B].
// Epilogue reuses [0, 33792) as yb[64n][33 f4] (padded).
#define AROW    1232
#define B_OFF   20480
#define LDS_SZ  (B_OFF + 14336)    // 34816 (x4 blocks = 139264 <= 160KB)

__device__ __forceinline__ void gl_lds16(const void* g, void* l) {
    __builtin_amdgcn_global_load_lds(
        (const __attribute__((address_space(1))) unsigned int*)g,
        (__attribute__((address_space(3))) unsigned int*)l, 16, 0, 0);
}

__device__ __forceinline__ void pair_ij(int p, int& i, int& j) {
    if (p < 3)      { i = p; j = p; }
    else if (p == 3){ i = 0; j = 1; }
    else if (p == 4){ i = 0; j = 2; }
    else            { i = 1; j = 2; }
}

struct bf2 { __hip_bfloat16 x, y; };
struct bh4 { __hip_bfloat16 x, y, z, w; };

// ---------------------------------------------------------------------------
// Merged prep: bid < 1372 -> build_w (tap = bid>>2, j-quarter), else build_xt.
// xt[chunk][brow][s][16ch], brow=(b*37+z)*37+y.  wl[chunk][tap][n][16ch].
// ---------------------------------------------------------------------------
__global__ void prep_kernel(
    const float* __restrict__ sv,
    const float* __restrict__ b_ss, const float* __restrict__ w_ss,
    const float* __restrict__ b_sv, const float* __restrict__ w_sv,
    const float* __restrict__ b_st, const float* __restrict__ w_st,
    const float* __restrict__ b_vs, const float* __restrict__ w_vs,
    const float* __restrict__ b_vv, const float* __restrict__ w_vv,
    const float* __restrict__ b_vt, const float* __restrict__ w_vt,
    __hip_bfloat16* __restrict__ xt, __hip_bfloat16* __restrict__ wl)
{
    __shared__ float S[13056];
    const int tid = threadIdx.x;

    if (blockIdx.x < 1372) {
        // ---------------- build_w ----------------
        float* L = S;           // 750
        float* W = S + 768;     // 12288
        const int tap = blockIdx.x >> 2;
        const int jq  = (blockIdx.x & 3) * 10;
        for (int r = tid; r < 750; r += 256) {
            float v;
            if (r < 3)        v = b_ss[r * NTAP + tap];
            else if (r < 12)  v = b_sv[(r - 3) * NTAP + tap];
            else if (r < 93)  v = b_st[(r - 12) * NTAP + tap];
            else if (r < 102) v = b_vs[(r - 93) * NTAP + tap];
            else if (r < 183) v = b_vv[(r - 102) * NTAP + tap];
            else              v = b_vt[(r - 183) * NTAP + tap];
            L[r] = v;
        }
        for (int r = tid; r < 12288; r += 256) {
            float v;
            if (r < 768)       v = w_ss[r];
            else if (r < 1536) v = w_sv[r - 768];
            else if (r < 3840) v = w_st[r - 1536];
            else if (r < 4608) v = w_vs[r - 3840];
            else if (r < 6912) v = w_vv[r - 4608];
            else               v = w_vt[r - 6912];
            W[r] = v;
        }
        __syncthreads();
        for (int j = jq; j < jq + 10; ++j) {
            const int idx = j * 256 + tid;
            const int c = idx % C_TOT, n = idx / C_TOT;
            float acc = 0.f;
            if (n < 16) {
                const int u = n;
                if (c < 16) {
                    for (int t = 0; t < 3; ++t) acc += W[(u*16 + c)*3 + t] * L[t];
                } else if (c < 64) {
                    int mm = (c-16)/3, di = (c-16)%3;
                    for (int t = 0; t < 3; ++t)
                        acc += W[768 + (u*16+mm)*3 + t] * L[3 + t*3 + di];
                } else {
                    int q = c-64, mm = q/6, p = q%6, i, jj;
                    pair_ij(p, i, jj);
                    int d1 = i*3+jj, d2 = jj*3+i;
                    for (int t = 0; t < 9; ++t) {
                        float bs = L[12 + t*9 + d1];
                        if (i != jj) bs += L[12 + t*9 + d2];
                        acc += W[1536 + (u*16+mm)*9 + t] * bs;
                    }
                }
            } else {
                const int u = (n-16)/3, dn = (n-16)%3;
                if (c < 16) {
                    for (int t = 0; t < 3; ++t)
                        acc += W[3840 + (u*16+c)*3 + t] * L[93 + t*3 + dn];
                } else if (c < 64) {
                    int mm = (c-16)/3, di = (c-16)%3;
                    for (int t = 0; t < 9; ++t)
                        acc += W[4608 + (u*16+mm)*9 + t] * L[102 + (t*3+dn)*3 + di];
                } else {
                    int q = c-64, mm = q/6, p = q%6, i, jj;
                    pair_ij(p, i, jj);
                    int d1 = i*3+jj, d2 = jj*3+i;
                    for (int t = 0; t < 21; ++t) {
                        float bs = L[183 + (t*3+dn)*9 + d1];
                        if (i != jj) bs += L[183 + (t*3+dn)*9 + d2];
                        acc += W[6912 + (u*16+mm)*21 + t] * bs;
                    }
                }
            }
            const int chunk = c >> 4, cw = c & 15;
            wl[((size_t)chunk * NTAP + tap) * 1024 + (size_t)n * 16 + cw] =
                __float2bfloat16(acc);
        }
    } else {
        // ---------------- build_xt ----------------
        float* row = S;                              // 32*66 = 2112
        const int bid = blockIdx.x - 1372;           // (b*37 + z)*37 + y
        const int y = bid % 37, z = (bid / 37) % 37, b = bid / 1369;
        const bool interior = (z >= 3 && z < 35 && y >= 3 && y < 35);
        if (interior) {
            const float* src = sv + (size_t)b * 2097152 + (z-3) * 1024 + (y-3) * 32;
            for (int f = tid; f < 2048; f += 256) {
                int ch = f >> 5, x = f & 31;
                row[x * 66 + ch] = src[(size_t)ch * 32768 + x];
            }
        }
        __syncthreads();
        for (int e2 = tid; e2 < 38 * 80; e2 += 256) {
            const int s = e2 / 80, cp = e2 % 80, c = cp * 2;
            float v0 = 0.f, v1 = 0.f;
            if (interior && s >= 3 && s < 35) {
                const int x = s - 3;
                if (c < 64) {
                    v0 = row[x * 66 + c];
                    v1 = row[x * 66 + c + 1];
                } else {
                    int q = c - 64, u = q / 6, p = q % 6, i, j;
                    pair_ij(p, i, j);
                    v0 = row[x * 66 + 16 + u * 3 + i] * row[x * 66 + 16 + u * 3 + j];
                    pair_ij(p + 1, i, j);
                    v1 = row[x * 66 + 16 + u * 3 + i] * row[x * 66 + 16 + u * 3 + j];
                }
            }
            bf2 w{__float2bfloat16(v0), __float2bfloat16(v1)};
            const int chunk = c >> 4, cw = c & 15;
            *(bf2*)(xt + ((size_t)chunk * NROW + bid) * 608 + s * 16 + cw) = w;
        }
    }
}

// ---------------------------------------------------------------------------
// Conv. Grid 64*KSN. bid = (mb>>3)*(8*KSN) + ks*8 + (mb&7). BALANCED flat
// K-split: t = ks..489 step 16 (30/31 iters per block). Hoisted staging.
// Epilogue: two-pass LDS transpose -> coalesced bf16 partial stores.
// ---------------------------------------------------------------------------
__global__ __launch_bounds__(256, 4) void conv_mfma_kernel(
    const __hip_bfloat16* __restrict__ xt,
    const __hip_bfloat16* __restrict__ wl,
    __hip_bfloat16* __restrict__ y4b)
{
    __shared__ __align__(16) char lds[LDS_SZ];

    const int bid  = blockIdx.x;
    const int low3 = bid & 7;
    const int rest = bid >> 3;
    const int ks   = rest % KSN;
    const int mb   = (rest / KSN) * 8 + low3;
    const int b    = mb >> 4;
    const int oz0 = ((mb >> 2) & 3) * 4;
    const int oy0 = (mb & 3) * 4;

    const int tid  = threadIdx.x;
    const int w    = tid >> 6;          // x-quarter
    const int lane = tid & 63;
    const int m    = lane & 31;
    const int h    = lane >> 5;         // k-half (8-ch group)

    // ---- per-lane invariant staging offsets (elements) + LDS dsts ----
    int  invA[5];  char* dstA[5];
#pragma unroll
    for (int k = 0; k < 5; ++k) {
        const int i = w + 4 * k;                 // < 20 always
        const int o = i * 1024 + lane * 16;
        int r = o / AROW;
        int rem = o - r * AROW;
        if (r > 15) { r = 15; rem = 0; }         // slack: dummy src
        if (rem >= 1216) rem = 0;                // row pad: dummy src
        const int s  = rem >> 5;
        const int cg = ((rem >> 4) & 1) ^ ((s >> 1) & 1);
        const int base_row = (b * PZ_ + 2 * (oz0 + (r >> 2))) * PZ_
                           + 2 * (oy0 + (r & 3));
        invA[k] = base_row * 608 + s * 16 + cg * 8;
        dstA[k] = lds + i * 1024;
    }
    int  invB[4];  char* dstB[4];  int nB = 0;
#pragma unroll
    for (int k = 0; k < 4; ++k) {
        const int i = w + 4 * k;
        if (i < 14) {
            const int kx = i >> 1, nt = i & 1;
            invB[k] = kx * 1024 + (nt * 32 + m) * 16 + h * 8;
            dstB[k] = lds + B_OFF + i * 1024;
            nB = k + 1;
        }
    }

    f16v acc[2][2];
    for (int t = 0; t < 2; ++t)
        for (int n = 0; n < 2; ++n)
            for (int k = 0; k < 16; ++k) acc[t][n][k] = 0.f;

    const int rA0   = ((m >> 4) << 2) + ((m >> 2) & 3);   // LDS row for t=0
    const int sbase = (w << 3) + ((m & 3) << 1);          // + kx -> x slot

    for (int t5 = ks; t5 < NT5; t5 += KSN) {
        const int chunk = t5 / 49;
        const int zy    = t5 - chunk * 49;
        const int kz = zy / 7, ky = zy - kz * 7;
        const int u_a = (chunk * NROW + kz * PZ_ + ky) * 608;   // uniform
        const int u_b = (chunk * NTAP + zy * 7) * 1024;         // uniform
        __syncthreads();

#pragma unroll
        for (int k = 0; k < 5; ++k)
            gl_lds16(xt + u_a + invA[k], dstA[k]);
#pragma unroll
        for (int k = 0; k < 4; ++k)
            if (k < nB) gl_lds16(wl + u_b + invB[k], dstB[k]);
        __syncthreads();                           // drains lds-DMA

#pragma unroll
        for (int kx = 0; kx < 7; ++kx) {
            const int s   = sbase + kx;
            const int cgp = h ^ ((s >> 1) & 1);
            const char* ap = lds + rA0 * AROW + s * 32 + cgp * 16;
            const s8 a0 = *(const s8*)(ap);
            const s8 a1 = *(const s8*)(ap + 8 * AROW);
            const char* bp = lds + B_OFF + kx * 2048 + h * 512 + m * 16;
            const s8 b0 = *(const s8*)(bp);
            const s8 b1 = *(const s8*)(bp + 1024);
            acc[0][0] = __builtin_amdgcn_mfma_f32_32x32x16_bf16(a0, b0, acc[0][0], 0, 0, 0);
            acc[0][1] = __builtin_amdgcn_mfma_f32_32x32x16_bf16(a0, b1, acc[0][1], 0, 0, 0);
            acc[1][0] = __builtin_amdgcn_mfma_f32_32x32x16_bf16(a1, b0, acc[1][0], 0, 0, 0);
            acc[1][1] = __builtin_amdgcn_mfma_f32_32x32x16_bf16(a1, b1, acc[1][1], 0, 0, 0);
        }
    }

    // ---- epilogue: two-pass LDS transpose, coalesced bf16 partial stores ----
    // C/D 32x32: col(n)=lane&31, row m32=(reg&3)+8*(reg>>2)+4*h  [m74/m101]
    const int nl = lane & 31;
    f4* yb = (f4*)lds;                  // [64n][33 f4] padded = 33792 B
    __hip_bfloat16* dst0 = y4b + (size_t)ks * SLICE_E + (size_t)(b * 64) * 4096;
#pragma unroll
    for (int t = 0; t < 2; ++t) {       // mz-half
        __syncthreads();                // prior readers (or compute) done
#pragma unroll
        for (int nt = 0; nt < 2; ++nt) {
            const int n = nt * 32 + nl;
#pragma unroll
            for (int q = 0; q < 4; ++q) {
                const int rr = 2 * q + h;          // spatial f4 = rr*4 + w
                f4 v = { acc[t][nt][4*q], acc[t][nt][4*q+1],
                         acc[t][nt][4*q+2], acc[t][nt][4*q+3] };
                yb[n * 33 + rr * 4 + w] = v;
            }
        }
        __syncthreads();
        for (int j = tid; j < 2048; j += 256) {
            const int n  = j >> 5, sp = j & 31;    // sp = rr*4 + wq
            f4 v = yb[n * 33 + sp];
            const int rr = sp >> 2, wq = sp & 3;
            const int my = rr & 3, mz = t * 2 + (rr >> 2);
            bh4 p{__float2bfloat16(v.x), __float2bfloat16(v.y),
                  __float2bfloat16(v.z), __float2bfloat16(v.w)};
            *(bh4*)(dst0 + (size_t)n * 4096 +
                    (oz0 + mz) * 256 + (oy0 + my) * 16 + wq * 4) = p;
        }
    }
}

// ---------------------------------------------------------------------------
// Combine KSN bf16 partials -> f32 yc + per-(n,b) sum of squares. 256 blocks.
// ---------------------------------------------------------------------------
__global__ void combine_reduce_kernel(const __hip_bfloat16* __restrict__ y4b,
                                      float* __restrict__ yc,
                                      float* __restrict__ sums2)
{
    const int n = blockIdx.x & 63, q = blockIdx.x >> 6;
    const size_t base = ((size_t)q * 64 + n) * 4096;
    float s = 0.f;
    for (int i = threadIdx.x; i < 1024; i += 256) {
        const size_t off = base + (size_t)i * 4;
        f4 v = {0.f, 0.f, 0.f, 0.f};
#pragma unroll
        for (int k = 0; k < KSN; ++k) {
            bh4 r = *(const bh4*)(y4b + off + (size_t)k * SLICE_E);
            v.x += (float)r.x; v.y += (float)r.y;
            v.z += (float)r.z; v.w += (float)r.w;
        }
        *(f4*)(yc + off) = v;
        s += v.x * v.x + v.y * v.y + v.z * v.z + v.w * v.w;
    }
    __shared__ float red[256];
    red[threadIdx.x] = s;
    __syncthreads();
    for (int st = 128; st > 0; st >>= 1) {
        if (threadIdx.x < st) red[threadIdx.x] += red[threadIdx.x + st];
        __syncthreads();
    }
    if (threadIdx.x == 0) sums2[n * 4 + q] = red[0];
}

// ---------------------------------------------------------------------------
__global__ void finalize_kernel(const float* __restrict__ yc,
                                const float* __restrict__ sums2,
                                const float* __restrict__ g_s,
                                const float* __restrict__ g_v,
                                const float* __restrict__ bias_s,
                                float* __restrict__ out)
{
    const int idx = blockIdx.x * 256 + threadIdx.x;   // exact grid, 1M
    const int n = (idx >> 12) & 63;
    float v = yc[idx];
    if (n < 16) {
        float sum = sums2[n*4] + sums2[n*4+1] + sums2[n*4+2] + sums2[n*4+3];
        float var = sum * (1.0f / 16384.0f);
        float sc  = g_s[n] / sqrtf(var + 1e-5f);
        v = fmaxf(v * sc + bias_s[n], 0.f);
    } else {
        int u = (n - 16) / 3;
        float sum = 0.f;
        for (int k = 0; k < 12; ++k) sum += sums2[(16 + u * 3) * 4 + k];
        float var = sum * (1.0f / 49152.0f);
        v = v * (g_v[u] / sqrtf(var + 1e-5f));
    }
    out[idx] = v;
}

// ---------------------------------------------------------------------------
extern "C" void kernel_launch(void* const* d_in, const int* in_sizes, int n_in,
                              void* d_out, int out_size, void* d_ws, size_t ws_size,
                              hipStream_t stream)
{
    const float* sv    = (const float*)d_in[0];
    const float* b_ss  = (const float*)d_in[1];
    const float* w_ss  = (const float*)d_in[2];
    const float* b_sv  = (const float*)d_in[3];
    const float* w_sv  = (const float*)d_in[4];
    const float* b_st  = (const float*)d_in[5];
    const float* w_st  = (const float*)d_in[6];
    const float* b_vs  = (const float*)d_in[7];
    const float* w_vs  = (const float*)d_in[8];
    const float* b_vv  = (const float*)d_in[9];
    const float* w_vv  = (const float*)d_in[10];
    const float* b_vt  = (const float*)d_in[11];
    const float* w_vt  = (const float*)d_in[12];
    const float* bn_gs = (const float*)d_in[13];
    const float* bn_gv = (const float*)d_in[14];
    const float* bias_s= (const float*)d_in[15];
    float* out = (float*)d_out;

    char* ws = (char*)d_ws;
    constexpr size_t XT_BYTES = (size_t)10 * NROW * 1216;      // 66,588,160
    constexpr size_t WL_BYTES = (size_t)10 * NTAP * 2048;      //  7,024,640
    constexpr size_t Y4_BYTES = (size_t)KSN * SLICE_E * 2;     // 33,554,432
    constexpr size_t YC_BYTES = (size_t)4 * 64 * 4096 * 4;     //  4,194,304

    __hip_bfloat16* xt  = (__hip_bfloat16*)ws;
    __hip_bfloat16* wl  = (__hip_bfloat16*)(ws + XT_BYTES);
    __hip_bfloat16* y4b = (__hip_bfloat16*)(ws + XT_BYTES + WL_BYTES);
    float* yc    = (float*)(ws + XT_BYTES + WL_BYTES + Y4_BYTES);
    float* sums2 = (float*)(ws + XT_BYTES + WL_BYTES + Y4_BYTES + YC_BYTES);

    prep_kernel<<<1372 + 5476, 256, 0, stream>>>(
        sv, b_ss, w_ss, b_sv, w_sv, b_st, w_st, b_vs, w_vs, b_vv, w_vv,
        b_vt, w_vt, xt, wl);
    conv_mfma_kernel<<<64 * KSN, 256, 0, stream>>>(xt, wl, y4b);
    combine_reduce_kernel<<<256, 256, 0, stream>>>(y4b, yc, sums2);
    finalize_kernel<<<4096, 256, 0, stream>>>(yc, sums2, bn_gs, bn_gv, bias_s, out);
}